// Round 10
// baseline (185.423 us; speedup 1.0000x reference)
//
#include <hip/hip_runtime.h>
#include <cmath>

// IPOT solver: n=32768 rows, K=512 cols, 20 iterations.
// PERSISTENT design: one cooperative kernel keeps Kb = bf16(exp(2C)) entirely
// in VGPRs (512 blocks x 512 threads x 32 packed dwords = 32 MB). Per
// iteration only the 16 KB tsum reduction touches memory; HBM traffic is the
// compulsory 128 MB (read C once, write Q*n once).
// Grid barrier (round-9 lesson: counter fetch-add serializes 128 RMWs/address
// ~8 us/iter): single-writer monotone flags — block leader STOREs
// flags[bid]=t+1 (agent scope), every thread polls exactly one flag.
// No fences in the hot path beyond one acquire; tsum read via agent-scope
// atomic loads (coherence point, immune to non-coherent XCD L2s).
// Fallback: round-8 split-kernel path (proven 185 us) if coop launch or
// occupancy fails.
//
// ws layout: Kb[32 MB bf16] (fallback only) | ctrl:
//   gsig[20][512] | tsum[19][8][512] | flags[512] uint

namespace {
constexpr int ROWS = 32768;
constexpr int COLS = 512;
constexpr int ITERS = 20;
constexpr float EPS = 1e-12f;
constexpr float A_M = 1.0f / 32768.0f;
constexpr float B_M = 1.0f / 512.0f;
constexpr float L2E2 = 2.8853900817779268f;  // 2/ln2: exp(2c)=exp2(c*L2E2)
constexpr int NSH = 8;
constexpr int SLAB_ROWS = ROWS / 8;
constexpr int GSIG_OFF = 0;
constexpr int TSUM_OFF = ITERS * COLS;
constexpr int FLAG_OFF = TSUM_OFF + (ITERS - 1) * NSH * COLS;  // float idx
constexpr size_t KB_BYTES = (size_t)ROWS * COLS * 2;  // 32 MB
constexpr size_t CTRL_FLOATS = (size_t)FLAG_OFF + 512;
// persistent geometry: 512 blocks x 8 waves x 8 rows/wave
constexpr int PBLK = 512;
constexpr int PRPW = 8;
// fallback geometry (round 8, proven)
constexpr int WPB = 4;
constexpr int MID_BLOCKS = 1024;
constexpr int MID_RPW = 8;
constexpr int BIG_BLOCKS = 2048;
constexpr int BIG_RPW = 4;

typedef float f4v __attribute__((ext_vector_type(4)));
}

__device__ __forceinline__ float bflo(unsigned u) {
  union { unsigned i; float f; } v; v.i = u << 16; return v.f;
}
__device__ __forceinline__ float bfhi(unsigned u) {
  union { unsigned i; float f; } v; v.i = u & 0xFFFF0000u; return v.f;
}
__device__ __forceinline__ unsigned f2bf(float f) {
  union { float f; unsigned u; } v; v.f = f;
  return (v.u + 0x7FFFu + ((v.u >> 16) & 1u)) >> 16;
}
__device__ __forceinline__ int row_base_mid(int bid, int wave) {
  return (bid & 7) * SLAB_ROWS + ((bid >> 3) * WPB + wave) * MID_RPW;
}
__device__ __forceinline__ int row_base_big(int bid, int wave) {
  return (bid & 7) * SLAB_ROWS + ((bid >> 3) * WPB + wave) * BIG_RPW;
}

// ---- zero: gsig[0]=1/K; zero tsum + flags ----
__global__ __launch_bounds__(256) void ipot_zero_kernel(float* __restrict__ ctrl) {
  const size_t stride = (size_t)gridDim.x * blockDim.x;
  const size_t gtid = (size_t)blockIdx.x * blockDim.x + threadIdx.x;
  if (gtid < COLS) ctrl[GSIG_OFF + gtid] = B_M;
  const size_t zsz = (size_t)(ITERS - 1) * NSH * COLS + 512;
  for (size_t i = gtid; i < zsz; i += stride) ctrl[TSUM_OFF + i] = 0.0f;
}

// ================= persistent cooperative kernel =================
__global__ __launch_bounds__(512, 4) void ipot_persist_kernel(
    const float* __restrict__ C, float* __restrict__ out,
    float* __restrict__ ctrl) {
  __shared__ float sig[COLS];
  __shared__ float part[8][COLS];
  const int tid = threadIdx.x;   // 0..511
  const int wave = tid >> 6;     // 0..7
  const int lane = tid & 63;
  const int slab = blockIdx.x & 7;
  const size_t row0 = ((size_t)blockIdx.x * 8 + wave) * PRPW;
  unsigned* flags = (unsigned*)(ctrl + FLAG_OFF);

  // ---- phase A: load C (NT), exp, pack bf16 into registers ----
  unsigned kb[PRPW][4];
  {
    const float* rp = C + row0 * COLS + 8 * lane;
    f4v c0 = __builtin_nontemporal_load((const f4v*)rp);
    f4v c1 = __builtin_nontemporal_load((const f4v*)(rp + 4));
#pragma unroll
    for (int r = 0; r < PRPW; ++r) {
      f4v d0 = c0, d1 = c1;
      if (r + 1 < PRPW) {
        const float* np = rp + (size_t)(r + 1) * COLS;
        c0 = __builtin_nontemporal_load((const f4v*)np);
        c1 = __builtin_nontemporal_load((const f4v*)(np + 4));
      }
      d0.x = exp2f(d0.x * L2E2); d0.y = exp2f(d0.y * L2E2);
      d0.z = exp2f(d0.z * L2E2); d0.w = exp2f(d0.w * L2E2);
      d1.x = exp2f(d1.x * L2E2); d1.y = exp2f(d1.y * L2E2);
      d1.z = exp2f(d1.z * L2E2); d1.w = exp2f(d1.w * L2E2);
      kb[r][0] = f2bf(d0.x) | (f2bf(d0.y) << 16);
      kb[r][1] = f2bf(d0.z) | (f2bf(d0.w) << 16);
      kb[r][2] = f2bf(d1.x) | (f2bf(d1.y) << 16);
      kb[r][3] = f2bf(d1.z) | (f2bf(d1.w) << 16);
    }
  }
  sig[tid] = B_M;
  __syncthreads();

  // ---- iterations t=0..18 ----
  for (int t = 0; t < ITERS - 1; ++t) {
    const float4 sA = *(const float4*)&sig[8 * lane];
    const float4 sB = *(const float4*)&sig[8 * lane + 4];
    float p[PRPW];
#pragma unroll
    for (int r = 0; r < PRPW; ++r) {
      p[r] = bflo(kb[r][0]) * sA.x + bfhi(kb[r][0]) * sA.y +
             bflo(kb[r][1]) * sA.z + bfhi(kb[r][1]) * sA.w +
             bflo(kb[r][2]) * sB.x + bfhi(kb[r][2]) * sB.y +
             bflo(kb[r][3]) * sB.z + bfhi(kb[r][3]) * sB.w;
    }
#pragma unroll
    for (int off = 32; off; off >>= 1) {
#pragma unroll
      for (int r = 0; r < PRPW; ++r) p[r] += __shfl_xor(p[r], off, 64);
    }
    float a[8] = {0.f, 0.f, 0.f, 0.f, 0.f, 0.f, 0.f, 0.f};
#pragma unroll
    for (int r = 0; r < PRPW; ++r) {
      const float inv = 1.0f / (p[r] + EPS);
      a[0] += bflo(kb[r][0]) * inv; a[1] += bfhi(kb[r][0]) * inv;
      a[2] += bflo(kb[r][1]) * inv; a[3] += bfhi(kb[r][1]) * inv;
      a[4] += bflo(kb[r][2]) * inv; a[5] += bfhi(kb[r][2]) * inv;
      a[6] += bflo(kb[r][3]) * inv; a[7] += bfhi(kb[r][3]) * inv;
    }
    *(float4*)&part[wave][8 * lane] = *(float4*)&a[0];
    *(float4*)&part[wave][8 * lane + 4] = *(float4*)&a[4];
    __syncthreads();

    // one column per thread: LDS combine 8 waves, one atomicAdd
    {
      float v = part[0][tid] + part[1][tid] + part[2][tid] + part[3][tid] +
                part[4][tid] + part[5][tid] + part[6][tid] + part[7][tid];
      float* ts = ctrl + TSUM_OFF + ((size_t)t * NSH + slab) * COLS;
      atomicAdd(&ts[tid], v);
    }

    // grid barrier t: syncthreads drains vmcnt (atomics done at coherence
    // point) -> leader STORES monotone flag -> all threads poll one flag each
    __syncthreads();
    if (tid == 0)
      __hip_atomic_store(&flags[blockIdx.x], (unsigned)(t + 1),
                         __ATOMIC_RELAXED, __HIP_MEMORY_SCOPE_AGENT);
    while (__hip_atomic_load(&flags[tid], __ATOMIC_RELAXED,
                             __HIP_MEMORY_SCOPE_AGENT) < (unsigned)(t + 1))
      __builtin_amdgcn_s_sleep(1);
    __syncthreads();
    __builtin_amdgcn_fence(__ATOMIC_ACQUIRE, "agent");

    // sigma update from tsum[t] (agent-scope atomic loads)
    const float* tb = ctrl + TSUM_OFF + (size_t)t * NSH * COLS;
    float T = 0.f;
#pragma unroll
    for (int s = 0; s < NSH; ++s)
      T += __hip_atomic_load(&tb[s * COLS + tid], __ATOMIC_RELAXED,
                             __HIP_MEMORY_SCOPE_AGENT);
    sig[tid] = B_M / (sig[tid] * A_M * T + EPS);
    __syncthreads();
  }

  // ---- final: Q*n = Kb*sigma19 / (Kb . sigma19), NT store ----
  {
    const float4 sA = *(const float4*)&sig[8 * lane];
    const float4 sB = *(const float4*)&sig[8 * lane + 4];
    float p[PRPW];
#pragma unroll
    for (int r = 0; r < PRPW; ++r) {
      p[r] = bflo(kb[r][0]) * sA.x + bfhi(kb[r][0]) * sA.y +
             bflo(kb[r][1]) * sA.z + bfhi(kb[r][1]) * sA.w +
             bflo(kb[r][2]) * sB.x + bfhi(kb[r][2]) * sB.y +
             bflo(kb[r][3]) * sB.z + bfhi(kb[r][3]) * sB.w;
    }
#pragma unroll
    for (int off = 32; off; off >>= 1) {
#pragma unroll
      for (int r = 0; r < PRPW; ++r) p[r] += __shfl_xor(p[r], off, 64);
    }
#pragma unroll
    for (int r = 0; r < PRPW; ++r) {
      const float inv = 1.0f / (p[r] + EPS);
      float* wp = out + (row0 + r) * COLS + 8 * lane;
      f4v o0, o1;
      o0.x = bflo(kb[r][0]) * sA.x * inv; o0.y = bfhi(kb[r][0]) * sA.y * inv;
      o0.z = bflo(kb[r][1]) * sA.z * inv; o0.w = bfhi(kb[r][1]) * sA.w * inv;
      o1.x = bflo(kb[r][2]) * sB.x * inv; o1.y = bfhi(kb[r][2]) * sB.y * inv;
      o1.z = bflo(kb[r][3]) * sB.z * inv; o1.w = bfhi(kb[r][3]) * sB.w * inv;
      __builtin_nontemporal_store(o0, (f4v*)wp);
      __builtin_nontemporal_store(o1, (f4v*)(wp + 4));
    }
  }
}

// ================= fallback: round-8 split path (proven) =================
template <bool NT_C>
__global__ __launch_bounds__(256, 8) void ipot_pass0_kernel(
    const float* __restrict__ C, unsigned short* __restrict__ Kb,
    float* __restrict__ ctrl) {
  __shared__ float part[WPB][COLS];
  const int tid = threadIdx.x;
  const int wave = tid >> 6;
  const int lane = tid & 63;
  const int wrow = row_base_big(blockIdx.x, wave);

  f4v c0[BIG_RPW], c1[BIG_RPW];
#pragma unroll
  for (int r = 0; r < BIG_RPW; ++r) {
    const f4v* rp = (const f4v*)(C + (size_t)(wrow + r) * COLS);
    if (NT_C) {
      c0[r] = __builtin_nontemporal_load(&rp[2 * lane]);
      c1[r] = __builtin_nontemporal_load(&rp[2 * lane + 1]);
    } else {
      c0[r] = rp[2 * lane];
      c1[r] = rp[2 * lane + 1];
    }
  }
  float p[BIG_RPW];
#pragma unroll
  for (int r = 0; r < BIG_RPW; ++r) {
    c0[r].x = exp2f(c0[r].x * L2E2); c0[r].y = exp2f(c0[r].y * L2E2);
    c0[r].z = exp2f(c0[r].z * L2E2); c0[r].w = exp2f(c0[r].w * L2E2);
    c1[r].x = exp2f(c1[r].x * L2E2); c1[r].y = exp2f(c1[r].y * L2E2);
    c1[r].z = exp2f(c1[r].z * L2E2); c1[r].w = exp2f(c1[r].w * L2E2);
    uint4 kp;
    kp.x = f2bf(c0[r].x) | (f2bf(c0[r].y) << 16);
    kp.y = f2bf(c0[r].z) | (f2bf(c0[r].w) << 16);
    kp.z = f2bf(c1[r].x) | (f2bf(c1[r].y) << 16);
    kp.w = f2bf(c1[r].z) | (f2bf(c1[r].w) << 16);
    ((uint4*)(Kb + (size_t)(wrow + r) * COLS))[lane] = kp;
    p[r] = ((c0[r].x + c0[r].y) + (c0[r].z + c0[r].w)) +
           ((c1[r].x + c1[r].y) + (c1[r].z + c1[r].w));
  }
#pragma unroll
  for (int off = 32; off; off >>= 1) {
#pragma unroll
    for (int r = 0; r < BIG_RPW; ++r) p[r] += __shfl_xor(p[r], off, 64);
  }
  float a[8] = {0.f, 0.f, 0.f, 0.f, 0.f, 0.f, 0.f, 0.f};
#pragma unroll
  for (int r = 0; r < BIG_RPW; ++r) {
    const float inv = 1.0f / (B_M * p[r] + EPS);
    a[0] += c0[r].x * inv; a[1] += c0[r].y * inv;
    a[2] += c0[r].z * inv; a[3] += c0[r].w * inv;
    a[4] += c1[r].x * inv; a[5] += c1[r].y * inv;
    a[6] += c1[r].z * inv; a[7] += c1[r].w * inv;
  }
  *(float4*)&part[wave][8 * lane] = *(float4*)&a[0];
  *(float4*)&part[wave][8 * lane + 4] = *(float4*)&a[4];
  __syncthreads();
  float* ts = ctrl + TSUM_OFF + (size_t)(blockIdx.x & 7) * COLS;
  int j = tid;
  atomicAdd(&ts[j], part[0][j] + part[1][j] + part[2][j] + part[3][j]);
  j += 256;
  atomicAdd(&ts[j], part[0][j] + part[1][j] + part[2][j] + part[3][j]);
}

__global__ __launch_bounds__(256, 4) void ipot_mid_kernel(
    const unsigned short* __restrict__ Kb, float* __restrict__ ctrl, int t) {
  __shared__ float sig[COLS];
  __shared__ float part[WPB][COLS];
  const int tid = threadIdx.x;
  const int wave = tid >> 6;
  const int lane = tid & 63;
  const int wrow = row_base_mid(blockIdx.x, wave);

  const float* gsp = ctrl + GSIG_OFF + (size_t)(t - 1) * COLS;
  const float* tb = ctrl + TSUM_OFF + (size_t)(t - 1) * NSH * COLS;
  float tv0[NSH], tv1[NSH];
#pragma unroll
  for (int s = 0; s < NSH; ++s) {
    tv0[s] = tb[s * COLS + tid];
    tv1[s] = tb[s * COLS + tid + 256];
  }
  const float g0 = gsp[tid];
  const float g1 = gsp[tid + 256];

  uint4 kr[MID_RPW];
#pragma unroll
  for (int r = 0; r < MID_RPW; ++r)
    kr[r] = ((const uint4*)(Kb + (size_t)(wrow + r) * COLS))[lane];
  {
    float T0 = 0.f, T1 = 0.f;
#pragma unroll
    for (int s = 0; s < NSH; ++s) { T0 += tv0[s]; T1 += tv1[s]; }
    const float sv0 = B_M / (g0 * A_M * T0 + EPS);
    const float sv1 = B_M / (g1 * A_M * T1 + EPS);
    sig[tid] = sv0;
    sig[tid + 256] = sv1;
    if (blockIdx.x == 0) {
      float* gsc = ctrl + GSIG_OFF + (size_t)t * COLS;
      gsc[tid] = sv0;
      gsc[tid + 256] = sv1;
    }
  }
  __syncthreads();

  const float4 sA = *(const float4*)&sig[8 * lane];
  const float4 sB = *(const float4*)&sig[8 * lane + 4];
  float p[MID_RPW];
#pragma unroll
  for (int r = 0; r < MID_RPW; ++r) {
    p[r] = bflo(kr[r].x) * sA.x + bfhi(kr[r].x) * sA.y +
           bflo(kr[r].y) * sA.z + bfhi(kr[r].y) * sA.w +
           bflo(kr[r].z) * sB.x + bfhi(kr[r].z) * sB.y +
           bflo(kr[r].w) * sB.z + bfhi(kr[r].w) * sB.w;
  }
#pragma unroll
  for (int off = 32; off; off >>= 1) {
#pragma unroll
    for (int r = 0; r < MID_RPW; ++r) p[r] += __shfl_xor(p[r], off, 64);
  }
  float a[8] = {0.f, 0.f, 0.f, 0.f, 0.f, 0.f, 0.f, 0.f};
#pragma unroll
  for (int r = 0; r < MID_RPW; ++r) {
    const float inv = 1.0f / (p[r] + EPS);
    a[0] += bflo(kr[r].x) * inv; a[1] += bfhi(kr[r].x) * inv;
    a[2] += bflo(kr[r].y) * inv; a[3] += bfhi(kr[r].y) * inv;
    a[4] += bflo(kr[r].z) * inv; a[5] += bfhi(kr[r].z) * inv;
    a[6] += bflo(kr[r].w) * inv; a[7] += bfhi(kr[r].w) * inv;
  }
  *(float4*)&part[wave][8 * lane] = *(float4*)&a[0];
  *(float4*)&part[wave][8 * lane + 4] = *(float4*)&a[4];
  __syncthreads();
  float* ts = ctrl + TSUM_OFF + ((size_t)t * NSH + (blockIdx.x & 7)) * COLS;
  int j = tid;
  atomicAdd(&ts[j], part[0][j] + part[1][j] + part[2][j] + part[3][j]);
  j += 256;
  atomicAdd(&ts[j], part[0][j] + part[1][j] + part[2][j] + part[3][j]);
}

__global__ __launch_bounds__(256, 8) void ipot_final_kb_kernel(
    const unsigned short* __restrict__ Kb, float* __restrict__ out,
    const float* __restrict__ ctrl) {
  __shared__ float sig[COLS];
  const int tid = threadIdx.x;
  const int wave = tid >> 6;
  const int lane = tid & 63;
  const int wrow = row_base_big(blockIdx.x, wave);

  const int t = ITERS - 1;
  const float* gsp = ctrl + GSIG_OFF + (size_t)(t - 1) * COLS;
  const float* tb = ctrl + TSUM_OFF + (size_t)(t - 1) * NSH * COLS;
  float tv0[NSH], tv1[NSH];
#pragma unroll
  for (int s = 0; s < NSH; ++s) {
    tv0[s] = tb[s * COLS + tid];
    tv1[s] = tb[s * COLS + tid + 256];
  }
  const float g0 = gsp[tid];
  const float g1 = gsp[tid + 256];

  uint4 kr[BIG_RPW];
#pragma unroll
  for (int r = 0; r < BIG_RPW; ++r)
    kr[r] = ((const uint4*)(Kb + (size_t)(wrow + r) * COLS))[lane];
  {
    float T0 = 0.f, T1 = 0.f;
#pragma unroll
    for (int s = 0; s < NSH; ++s) { T0 += tv0[s]; T1 += tv1[s]; }
    sig[tid] = B_M / (g0 * A_M * T0 + EPS);
    sig[tid + 256] = B_M / (g1 * A_M * T1 + EPS);
  }
  __syncthreads();

  const float4 sA = *(const float4*)&sig[8 * lane];
  const float4 sB = *(const float4*)&sig[8 * lane + 4];
  float p[BIG_RPW];
#pragma unroll
  for (int r = 0; r < BIG_RPW; ++r) {
    p[r] = bflo(kr[r].x) * sA.x + bfhi(kr[r].x) * sA.y +
           bflo(kr[r].y) * sA.z + bfhi(kr[r].y) * sA.w +
           bflo(kr[r].z) * sB.x + bfhi(kr[r].z) * sB.y +
           bflo(kr[r].w) * sB.z + bfhi(kr[r].w) * sB.w;
  }
#pragma unroll
  for (int off = 32; off; off >>= 1) {
#pragma unroll
    for (int r = 0; r < BIG_RPW; ++r) p[r] += __shfl_xor(p[r], off, 64);
  }
#pragma unroll
  for (int r = 0; r < BIG_RPW; ++r) {
    const float inv = 1.0f / (p[r] + EPS);
    f4v* wp = (f4v*)(out + (size_t)(wrow + r) * COLS);
    f4v o0, o1;
    o0.x = bflo(kr[r].x) * sA.x * inv; o0.y = bfhi(kr[r].x) * sA.y * inv;
    o0.z = bflo(kr[r].y) * sA.z * inv; o0.w = bfhi(kr[r].y) * sA.w * inv;
    o1.x = bflo(kr[r].z) * sB.x * inv; o1.y = bfhi(kr[r].z) * sB.y * inv;
    o1.z = bflo(kr[r].w) * sB.z * inv; o1.w = bfhi(kr[r].w) * sB.w * inv;
    __builtin_nontemporal_store(o0, &wp[2 * lane]);
    __builtin_nontemporal_store(o1, &wp[2 * lane + 1]);
  }
}

extern "C" void kernel_launch(void* const* d_in, const int* in_sizes, int n_in,
                              void* d_out, int out_size, void* d_ws, size_t ws_size,
                              hipStream_t stream) {
  const float* C = (const float*)d_in[0];
  float* out = (float*)d_out;
  unsigned short* Kb = (unsigned short*)d_ws;
  float* ctrl = (float*)((char*)d_ws + KB_BYTES);
  const bool ws_ok = ws_size >= KB_BYTES + CTRL_FLOATS * sizeof(float);
  if (!ws_ok) ctrl = (float*)d_ws;

  ipot_zero_kernel<<<128, 256, 0, stream>>>(ctrl);

  // persistent path requires 2 co-resident 512-thread blocks per CU
  int occ = 0;
  hipError_t oe = hipOccupancyMaxActiveBlocksPerMultiprocessor(
      &occ, reinterpret_cast<const void*>(&ipot_persist_kernel), 512, 0);
  bool persist = ws_ok && (oe == hipSuccess) && (occ >= 2);
  if (persist) {
    void* args[] = {(void*)&C, (void*)&out, (void*)&ctrl};
    hipError_t ce = hipLaunchCooperativeKernel(
        reinterpret_cast<void*>(&ipot_persist_kernel), dim3(PBLK), dim3(512),
        args, 0, stream);
    if (ce != hipSuccess) persist = false;
  }
  if (!persist) {
    ipot_pass0_kernel<true><<<BIG_BLOCKS, 256, 0, stream>>>(C, Kb, ctrl);
    for (int t = 1; t < ITERS - 1; ++t)
      ipot_mid_kernel<<<MID_BLOCKS, 256, 0, stream>>>(Kb, ctrl, t);
    ipot_final_kb_kernel<<<BIG_BLOCKS, 256, 0, stream>>>(Kb, out, ctrl);
  }
}

// Round 11
// 185.034 us; speedup vs baseline: 1.0021x; 1.0021x over previous
//
#include <hip/hip_runtime.h>
#include <cmath>

// IPOT solver: n=32768 rows, K=512 cols, 20 iterations.
// PERSISTENT v3: one cooperative kernel, Kb = bf16(exp(2C)) resident in VGPRs
// (256 blocks x 1024 threads x 32 packed dwords = 32 MB). Per iteration the
// only memory traffic is the 512-float allreduce.
// Round-10 lesson: barrier mechanism (flags vs counters vs relaunch) all cost
// ~7 us/iter -> the common serial term was the tsum RMW chain (64 serialized
// RMWs/address with NSH=8). This round: NSH=32 (8 RMWs/address), 256 blocks
// (half fan-in), wave0-only polling.
// ws layout: Kb[32 MB bf16] (fallback only) | ctrl:
//   gsig[20][512] | tsum[19][32][512] | flags[256] uint

namespace {
constexpr int ROWS = 32768;
constexpr int COLS = 512;
constexpr int ITERS = 20;
constexpr float EPS = 1e-12f;
constexpr float A_M = 1.0f / 32768.0f;
constexpr float B_M = 1.0f / 512.0f;
constexpr float L2E2 = 2.8853900817779268f;  // 2/ln2: exp(2c)=exp2(c*L2E2)
constexpr int GSIG_OFF = 0;
constexpr int TSUM_OFF = ITERS * COLS;
constexpr int NSHP = 32;                     // persistent shadows
constexpr int FLAG_OFF = TSUM_OFF + (ITERS - 1) * NSHP * COLS;
constexpr size_t KB_BYTES = (size_t)ROWS * COLS * 2;  // 32 MB
constexpr size_t CTRL_FLOATS = (size_t)FLAG_OFF + 256;
// persistent geometry: 256 blocks x 16 waves x 8 rows/wave
constexpr int PBLK = 256;
constexpr int PWAVES = 16;
constexpr int PRPW = 8;
// fallback geometry (round 8, proven)
constexpr int NSHF = 8;
constexpr int WPB = 4;
constexpr int MID_BLOCKS = 1024;
constexpr int MID_RPW = 8;
constexpr int BIG_BLOCKS = 2048;
constexpr int BIG_RPW = 4;
constexpr int SLAB_ROWS = ROWS / 8;

typedef float f4v __attribute__((ext_vector_type(4)));
}

__device__ __forceinline__ float bflo(unsigned u) {
  union { unsigned i; float f; } v; v.i = u << 16; return v.f;
}
__device__ __forceinline__ float bfhi(unsigned u) {
  union { unsigned i; float f; } v; v.i = u & 0xFFFF0000u; return v.f;
}
__device__ __forceinline__ unsigned f2bf(float f) {
  union { float f; unsigned u; } v; v.f = f;
  return (v.u + 0x7FFFu + ((v.u >> 16) & 1u)) >> 16;
}
__device__ __forceinline__ int row_base_mid(int bid, int wave) {
  return (bid & 7) * SLAB_ROWS + ((bid >> 3) * WPB + wave) * MID_RPW;
}
__device__ __forceinline__ int row_base_big(int bid, int wave) {
  return (bid & 7) * SLAB_ROWS + ((bid >> 3) * WPB + wave) * BIG_RPW;
}

// ---- zero: gsig[0]=1/K; zero tsum (NSHP-sized region) + flags ----
__global__ __launch_bounds__(256) void ipot_zero_kernel(float* __restrict__ ctrl) {
  const size_t stride = (size_t)gridDim.x * blockDim.x;
  const size_t gtid = (size_t)blockIdx.x * blockDim.x + threadIdx.x;
  if (gtid < COLS) ctrl[GSIG_OFF + gtid] = B_M;
  const size_t zsz = (size_t)(ITERS - 1) * NSHP * COLS + 256;
  for (size_t i = gtid; i < zsz; i += stride) ctrl[TSUM_OFF + i] = 0.0f;
}

// ================= persistent cooperative kernel =================
__global__ __launch_bounds__(1024, 4) void ipot_persist_kernel(
    const float* __restrict__ C, float* __restrict__ out,
    float* __restrict__ ctrl) {
  __shared__ float sig[COLS];
  __shared__ float part[PWAVES][COLS];
  const int tid = threadIdx.x;   // 0..1023
  const int wave = tid >> 6;     // 0..15
  const int lane = tid & 63;
  const int shadow = blockIdx.x & (NSHP - 1);
  const size_t row0 = ((size_t)blockIdx.x * PWAVES + wave) * PRPW;
  unsigned* flags = (unsigned*)(ctrl + FLAG_OFF);

  // ---- phase A: load C (NT), exp, pack bf16 into registers ----
  unsigned kb[PRPW][4];
  {
    const float* rp = C + row0 * COLS + 8 * lane;
    f4v c0 = __builtin_nontemporal_load((const f4v*)rp);
    f4v c1 = __builtin_nontemporal_load((const f4v*)(rp + 4));
#pragma unroll
    for (int r = 0; r < PRPW; ++r) {
      f4v d0 = c0, d1 = c1;
      if (r + 1 < PRPW) {
        const float* np = rp + (size_t)(r + 1) * COLS;
        c0 = __builtin_nontemporal_load((const f4v*)np);
        c1 = __builtin_nontemporal_load((const f4v*)(np + 4));
      }
      d0.x = exp2f(d0.x * L2E2); d0.y = exp2f(d0.y * L2E2);
      d0.z = exp2f(d0.z * L2E2); d0.w = exp2f(d0.w * L2E2);
      d1.x = exp2f(d1.x * L2E2); d1.y = exp2f(d1.y * L2E2);
      d1.z = exp2f(d1.z * L2E2); d1.w = exp2f(d1.w * L2E2);
      kb[r][0] = f2bf(d0.x) | (f2bf(d0.y) << 16);
      kb[r][1] = f2bf(d0.z) | (f2bf(d0.w) << 16);
      kb[r][2] = f2bf(d1.x) | (f2bf(d1.y) << 16);
      kb[r][3] = f2bf(d1.z) | (f2bf(d1.w) << 16);
    }
  }
  if (tid < COLS) sig[tid] = B_M;
  __syncthreads();

  // ---- iterations t=0..18 ----
  for (int t = 0; t < ITERS - 1; ++t) {
    const float4 sA = *(const float4*)&sig[8 * lane];
    const float4 sB = *(const float4*)&sig[8 * lane + 4];
    float p[PRPW];
#pragma unroll
    for (int r = 0; r < PRPW; ++r) {
      p[r] = bflo(kb[r][0]) * sA.x + bfhi(kb[r][0]) * sA.y +
             bflo(kb[r][1]) * sA.z + bfhi(kb[r][1]) * sA.w +
             bflo(kb[r][2]) * sB.x + bfhi(kb[r][2]) * sB.y +
             bflo(kb[r][3]) * sB.z + bfhi(kb[r][3]) * sB.w;
    }
#pragma unroll
    for (int off = 32; off; off >>= 1) {
#pragma unroll
      for (int r = 0; r < PRPW; ++r) p[r] += __shfl_xor(p[r], off, 64);
    }
    float a[8] = {0.f, 0.f, 0.f, 0.f, 0.f, 0.f, 0.f, 0.f};
#pragma unroll
    for (int r = 0; r < PRPW; ++r) {
      const float inv = 1.0f / (p[r] + EPS);
      a[0] += bflo(kb[r][0]) * inv; a[1] += bfhi(kb[r][0]) * inv;
      a[2] += bflo(kb[r][1]) * inv; a[3] += bfhi(kb[r][1]) * inv;
      a[4] += bflo(kb[r][2]) * inv; a[5] += bfhi(kb[r][2]) * inv;
      a[6] += bflo(kb[r][3]) * inv; a[7] += bfhi(kb[r][3]) * inv;
    }
    *(float4*)&part[wave][8 * lane] = *(float4*)&a[0];
    *(float4*)&part[wave][8 * lane + 4] = *(float4*)&a[4];
    __syncthreads();

    // one column per thread (tid<512): combine 16 waves, one atomicAdd
    if (tid < COLS) {
      float v = 0.f;
#pragma unroll
      for (int w = 0; w < PWAVES; ++w) v += part[w][tid];
      float* ts = ctrl + TSUM_OFF + ((size_t)t * NSHP + shadow) * COLS;
      atomicAdd(&ts[tid], v);
    }

    // grid barrier: syncthreads drains atomics -> leader stores monotone
    // flag -> wave 0 polls all 256 flags (4/lane), others park at barrier
    __syncthreads();
    if (tid == 0)
      __hip_atomic_store(&flags[blockIdx.x], (unsigned)(t + 1),
                         __ATOMIC_RELAXED, __HIP_MEMORY_SCOPE_AGENT);
    if (wave == 0) {
      const unsigned want = (unsigned)(t + 1);
      for (;;) {
        unsigned m0 = __hip_atomic_load(&flags[lane], __ATOMIC_RELAXED,
                                        __HIP_MEMORY_SCOPE_AGENT);
        unsigned m1 = __hip_atomic_load(&flags[lane + 64], __ATOMIC_RELAXED,
                                        __HIP_MEMORY_SCOPE_AGENT);
        unsigned m2 = __hip_atomic_load(&flags[lane + 128], __ATOMIC_RELAXED,
                                        __HIP_MEMORY_SCOPE_AGENT);
        unsigned m3 = __hip_atomic_load(&flags[lane + 192], __ATOMIC_RELAXED,
                                        __HIP_MEMORY_SCOPE_AGENT);
        unsigned mn = min(min(m0, m1), min(m2, m3));
        if (__all(mn >= want)) break;
        __builtin_amdgcn_s_sleep(1);
      }
    }
    __syncthreads();
    __builtin_amdgcn_fence(__ATOMIC_ACQUIRE, "agent");

    // sigma update from tsum[t] (agent-scope atomic loads)
    if (tid < COLS) {
      const float* tb = ctrl + TSUM_OFF + (size_t)t * NSHP * COLS;
      float T = 0.f;
#pragma unroll
      for (int s = 0; s < NSHP; ++s)
        T += __hip_atomic_load(&tb[s * COLS + tid], __ATOMIC_RELAXED,
                               __HIP_MEMORY_SCOPE_AGENT);
      sig[tid] = B_M / (sig[tid] * A_M * T + EPS);
    }
    __syncthreads();
  }

  // ---- final: Q*n = Kb*sigma19 / (Kb . sigma19), NT store ----
  {
    const float4 sA = *(const float4*)&sig[8 * lane];
    const float4 sB = *(const float4*)&sig[8 * lane + 4];
    float p[PRPW];
#pragma unroll
    for (int r = 0; r < PRPW; ++r) {
      p[r] = bflo(kb[r][0]) * sA.x + bfhi(kb[r][0]) * sA.y +
             bflo(kb[r][1]) * sA.z + bfhi(kb[r][1]) * sA.w +
             bflo(kb[r][2]) * sB.x + bfhi(kb[r][2]) * sB.y +
             bflo(kb[r][3]) * sB.z + bfhi(kb[r][3]) * sB.w;
    }
#pragma unroll
    for (int off = 32; off; off >>= 1) {
#pragma unroll
      for (int r = 0; r < PRPW; ++r) p[r] += __shfl_xor(p[r], off, 64);
    }
#pragma unroll
    for (int r = 0; r < PRPW; ++r) {
      const float inv = 1.0f / (p[r] + EPS);
      float* wp = out + (row0 + r) * COLS + 8 * lane;
      f4v o0, o1;
      o0.x = bflo(kb[r][0]) * sA.x * inv; o0.y = bfhi(kb[r][0]) * sA.y * inv;
      o0.z = bflo(kb[r][1]) * sA.z * inv; o0.w = bfhi(kb[r][1]) * sA.w * inv;
      o1.x = bflo(kb[r][2]) * sB.x * inv; o1.y = bfhi(kb[r][2]) * sB.y * inv;
      o1.z = bflo(kb[r][3]) * sB.z * inv; o1.w = bfhi(kb[r][3]) * sB.w * inv;
      __builtin_nontemporal_store(o0, (f4v*)wp);
      __builtin_nontemporal_store(o1, (f4v*)(wp + 4));
    }
  }
}

// ================= fallback: round-8 split path (proven) =================
template <bool NT_C>
__global__ __launch_bounds__(256, 8) void ipot_pass0_kernel(
    const float* __restrict__ C, unsigned short* __restrict__ Kb,
    float* __restrict__ ctrl) {
  __shared__ float part[WPB][COLS];
  const int tid = threadIdx.x;
  const int wave = tid >> 6;
  const int lane = tid & 63;
  const int wrow = row_base_big(blockIdx.x, wave);

  f4v c0[BIG_RPW], c1[BIG_RPW];
#pragma unroll
  for (int r = 0; r < BIG_RPW; ++r) {
    const f4v* rp = (const f4v*)(C + (size_t)(wrow + r) * COLS);
    if (NT_C) {
      c0[r] = __builtin_nontemporal_load(&rp[2 * lane]);
      c1[r] = __builtin_nontemporal_load(&rp[2 * lane + 1]);
    } else {
      c0[r] = rp[2 * lane];
      c1[r] = rp[2 * lane + 1];
    }
  }
  float p[BIG_RPW];
#pragma unroll
  for (int r = 0; r < BIG_RPW; ++r) {
    c0[r].x = exp2f(c0[r].x * L2E2); c0[r].y = exp2f(c0[r].y * L2E2);
    c0[r].z = exp2f(c0[r].z * L2E2); c0[r].w = exp2f(c0[r].w * L2E2);
    c1[r].x = exp2f(c1[r].x * L2E2); c1[r].y = exp2f(c1[r].y * L2E2);
    c1[r].z = exp2f(c1[r].z * L2E2); c1[r].w = exp2f(c1[r].w * L2E2);
    uint4 kp;
    kp.x = f2bf(c0[r].x) | (f2bf(c0[r].y) << 16);
    kp.y = f2bf(c0[r].z) | (f2bf(c0[r].w) << 16);
    kp.z = f2bf(c1[r].x) | (f2bf(c1[r].y) << 16);
    kp.w = f2bf(c1[r].z) | (f2bf(c1[r].w) << 16);
    ((uint4*)(Kb + (size_t)(wrow + r) * COLS))[lane] = kp;
    p[r] = ((c0[r].x + c0[r].y) + (c0[r].z + c0[r].w)) +
           ((c1[r].x + c1[r].y) + (c1[r].z + c1[r].w));
  }
#pragma unroll
  for (int off = 32; off; off >>= 1) {
#pragma unroll
    for (int r = 0; r < BIG_RPW; ++r) p[r] += __shfl_xor(p[r], off, 64);
  }
  float a[8] = {0.f, 0.f, 0.f, 0.f, 0.f, 0.f, 0.f, 0.f};
#pragma unroll
  for (int r = 0; r < BIG_RPW; ++r) {
    const float inv = 1.0f / (B_M * p[r] + EPS);
    a[0] += c0[r].x * inv; a[1] += c0[r].y * inv;
    a[2] += c0[r].z * inv; a[3] += c0[r].w * inv;
    a[4] += c1[r].x * inv; a[5] += c1[r].y * inv;
    a[6] += c1[r].z * inv; a[7] += c1[r].w * inv;
  }
  *(float4*)&part[wave][8 * lane] = *(float4*)&a[0];
  *(float4*)&part[wave][8 * lane + 4] = *(float4*)&a[4];
  __syncthreads();
  float* ts = ctrl + TSUM_OFF + (size_t)(blockIdx.x & 7) * COLS;
  int j = tid;
  atomicAdd(&ts[j], part[0][j] + part[1][j] + part[2][j] + part[3][j]);
  j += 256;
  atomicAdd(&ts[j], part[0][j] + part[1][j] + part[2][j] + part[3][j]);
}

__global__ __launch_bounds__(256, 4) void ipot_mid_kernel(
    const unsigned short* __restrict__ Kb, float* __restrict__ ctrl, int t) {
  __shared__ float sig[COLS];
  __shared__ float part[WPB][COLS];
  const int tid = threadIdx.x;
  const int wave = tid >> 6;
  const int lane = tid & 63;
  const int wrow = row_base_mid(blockIdx.x, wave);

  const float* gsp = ctrl + GSIG_OFF + (size_t)(t - 1) * COLS;
  const float* tb = ctrl + TSUM_OFF + (size_t)(t - 1) * NSHF * COLS;
  float tv0[NSHF], tv1[NSHF];
#pragma unroll
  for (int s = 0; s < NSHF; ++s) {
    tv0[s] = tb[s * COLS + tid];
    tv1[s] = tb[s * COLS + tid + 256];
  }
  const float g0 = gsp[tid];
  const float g1 = gsp[tid + 256];

  uint4 kr[MID_RPW];
#pragma unroll
  for (int r = 0; r < MID_RPW; ++r)
    kr[r] = ((const uint4*)(Kb + (size_t)(wrow + r) * COLS))[lane];
  {
    float T0 = 0.f, T1 = 0.f;
#pragma unroll
    for (int s = 0; s < NSHF; ++s) { T0 += tv0[s]; T1 += tv1[s]; }
    const float sv0 = B_M / (g0 * A_M * T0 + EPS);
    const float sv1 = B_M / (g1 * A_M * T1 + EPS);
    sig[tid] = sv0;
    sig[tid + 256] = sv1;
    if (blockIdx.x == 0) {
      float* gsc = ctrl + GSIG_OFF + (size_t)t * COLS;
      gsc[tid] = sv0;
      gsc[tid + 256] = sv1;
    }
  }
  __syncthreads();

  const float4 sA = *(const float4*)&sig[8 * lane];
  const float4 sB = *(const float4*)&sig[8 * lane + 4];
  float p[MID_RPW];
#pragma unroll
  for (int r = 0; r < MID_RPW; ++r) {
    p[r] = bflo(kr[r].x) * sA.x + bfhi(kr[r].x) * sA.y +
           bflo(kr[r].y) * sA.z + bfhi(kr[r].y) * sA.w +
           bflo(kr[r].z) * sB.x + bfhi(kr[r].z) * sB.y +
           bflo(kr[r].w) * sB.z + bfhi(kr[r].w) * sB.w;
  }
#pragma unroll
  for (int off = 32; off; off >>= 1) {
#pragma unroll
    for (int r = 0; r < MID_RPW; ++r) p[r] += __shfl_xor(p[r], off, 64);
  }
  float a[8] = {0.f, 0.f, 0.f, 0.f, 0.f, 0.f, 0.f, 0.f};
#pragma unroll
  for (int r = 0; r < MID_RPW; ++r) {
    const float inv = 1.0f / (p[r] + EPS);
    a[0] += bflo(kr[r].x) * inv; a[1] += bfhi(kr[r].x) * inv;
    a[2] += bflo(kr[r].y) * inv; a[3] += bfhi(kr[r].y) * inv;
    a[4] += bflo(kr[r].z) * inv; a[5] += bfhi(kr[r].z) * inv;
    a[6] += bflo(kr[r].w) * inv; a[7] += bfhi(kr[r].w) * inv;
  }
  *(float4*)&part[wave][8 * lane] = *(float4*)&a[0];
  *(float4*)&part[wave][8 * lane + 4] = *(float4*)&a[4];
  __syncthreads();
  float* ts = ctrl + TSUM_OFF + ((size_t)t * NSHF + (blockIdx.x & 7)) * COLS;
  int j = tid;
  atomicAdd(&ts[j], part[0][j] + part[1][j] + part[2][j] + part[3][j]);
  j += 256;
  atomicAdd(&ts[j], part[0][j] + part[1][j] + part[2][j] + part[3][j]);
}

__global__ __launch_bounds__(256, 8) void ipot_final_kb_kernel(
    const unsigned short* __restrict__ Kb, float* __restrict__ out,
    const float* __restrict__ ctrl) {
  __shared__ float sig[COLS];
  const int tid = threadIdx.x;
  const int wave = tid >> 6;
  const int lane = tid & 63;
  const int wrow = row_base_big(blockIdx.x, wave);

  const int t = ITERS - 1;
  const float* gsp = ctrl + GSIG_OFF + (size_t)(t - 1) * COLS;
  const float* tb = ctrl + TSUM_OFF + (size_t)(t - 1) * NSHF * COLS;
  float tv0[NSHF], tv1[NSHF];
#pragma unroll
  for (int s = 0; s < NSHF; ++s) {
    tv0[s] = tb[s * COLS + tid];
    tv1[s] = tb[s * COLS + tid + 256];
  }
  const float g0 = gsp[tid];
  const float g1 = gsp[tid + 256];

  uint4 kr[BIG_RPW];
#pragma unroll
  for (int r = 0; r < BIG_RPW; ++r)
    kr[r] = ((const uint4*)(Kb + (size_t)(wrow + r) * COLS))[lane];
  {
    float T0 = 0.f, T1 = 0.f;
#pragma unroll
    for (int s = 0; s < NSHF; ++s) { T0 += tv0[s]; T1 += tv1[s]; }
    sig[tid] = B_M / (g0 * A_M * T0 + EPS);
    sig[tid + 256] = B_M / (g1 * A_M * T1 + EPS);
  }
  __syncthreads();

  const float4 sA = *(const float4*)&sig[8 * lane];
  const float4 sB = *(const float4*)&sig[8 * lane + 4];
  float p[BIG_RPW];
#pragma unroll
  for (int r = 0; r < BIG_RPW; ++r) {
    p[r] = bflo(kr[r].x) * sA.x + bfhi(kr[r].x) * sA.y +
           bflo(kr[r].y) * sA.z + bfhi(kr[r].y) * sA.w +
           bflo(kr[r].z) * sB.x + bfhi(kr[r].z) * sB.y +
           bflo(kr[r].w) * sB.z + bfhi(kr[r].w) * sB.w;
  }
#pragma unroll
  for (int off = 32; off; off >>= 1) {
#pragma unroll
    for (int r = 0; r < BIG_RPW; ++r) p[r] += __shfl_xor(p[r], off, 64);
  }
#pragma unroll
  for (int r = 0; r < BIG_RPW; ++r) {
    const float inv = 1.0f / (p[r] + EPS);
    f4v* wp = (f4v*)(out + (size_t)(wrow + r) * COLS);
    f4v o0, o1;
    o0.x = bflo(kr[r].x) * sA.x * inv; o0.y = bfhi(kr[r].x) * sA.y * inv;
    o0.z = bflo(kr[r].y) * sA.z * inv; o0.w = bfhi(kr[r].y) * sA.w * inv;
    o1.x = bflo(kr[r].z) * sB.x * inv; o1.y = bfhi(kr[r].z) * sB.y * inv;
    o1.z = bflo(kr[r].w) * sB.z * inv; o1.w = bfhi(kr[r].w) * sB.w * inv;
    __builtin_nontemporal_store(o0, &wp[2 * lane]);
    __builtin_nontemporal_store(o1, &wp[2 * lane + 1]);
  }
}

extern "C" void kernel_launch(void* const* d_in, const int* in_sizes, int n_in,
                              void* d_out, int out_size, void* d_ws, size_t ws_size,
                              hipStream_t stream) {
  const float* C = (const float*)d_in[0];
  float* out = (float*)d_out;
  unsigned short* Kb = (unsigned short*)d_ws;
  float* ctrl = (float*)((char*)d_ws + KB_BYTES);
  const bool ws_ok = ws_size >= KB_BYTES + CTRL_FLOATS * sizeof(float);
  if (!ws_ok) ctrl = (float*)d_ws;

  ipot_zero_kernel<<<256, 256, 0, stream>>>(ctrl);

  // persistent path requires 1 co-resident 1024-thread block per CU
  int occ = 0;
  hipError_t oe = hipOccupancyMaxActiveBlocksPerMultiprocessor(
      &occ, reinterpret_cast<const void*>(&ipot_persist_kernel), 1024, 0);
  bool persist = ws_ok && (oe == hipSuccess) && (occ >= 1);
  if (persist) {
    void* args[] = {(void*)&C, (void*)&out, (void*)&ctrl};
    hipError_t ce = hipLaunchCooperativeKernel(
        reinterpret_cast<void*>(&ipot_persist_kernel), dim3(PBLK), dim3(1024),
        args, 0, stream);
    if (ce != hipSuccess) persist = false;
  }
  if (!persist) {
    ipot_pass0_kernel<true><<<BIG_BLOCKS, 256, 0, stream>>>(C, Kb, ctrl);
    for (int t = 1; t < ITERS - 1; ++t)
      ipot_mid_kernel<<<MID_BLOCKS, 256, 0, stream>>>(Kb, ctrl, t);
    ipot_final_kb_kernel<<<BIG_BLOCKS, 256, 0, stream>>>(Kb, out, ctrl);
  }
}

// Round 12
// 178.807 us; speedup vs baseline: 1.0370x; 1.0348x over previous
//
#include <hip/hip_runtime.h>
#include <cmath>

// IPOT solver: n=32768 rows, K=512 cols, 20 iterations.
// FINAL (round-7 configuration — session best, 179.2 us measured).
// zero -> fused(exp(2C)->bf16 Kb + iteration 0) -> 18 mid passes (bf16) ->
// final pass (fp32 exp recompute, writes Q*n).
// Sigma ordering: pass t's preamble recomputes sigma_t redundantly per block
// from gsig[t-1] + tsum[t-1]; block 0 persists gsig[t]. Kernel boundaries
// order everything (no fences/tickets — round-4 lesson: ~120 us/pass).
// Kb (32 MB, bf16) lives in the upper half of d_out across the mid passes;
// the final pass recomputes exp from fp32 C (never reads Kb) so overwriting
// d_out is race-free.
// Session floor analysis (rounds 8-11): per-iteration global allreduce+
// broadcast costs ~7-8.5 us on this 8-XCD part regardless of mechanism
// (kernel relaunch == flag barrier == counter barrier); 19 iterations of
// that plus ~35-40 us of compulsory HBM endpoints puts the structural floor
// at ~175-195 us. This kernel measures at the bottom of that band.
//
// ws float layout: gsig[20][512] | tsum[19][8][512]  (= 344 KB)

namespace {
constexpr int ROWS = 32768;
constexpr int COLS = 512;
constexpr int ITERS = 20;
constexpr float EPS = 1e-12f;
constexpr float A_M = 1.0f / 32768.0f;
constexpr float B_M = 1.0f / 512.0f;
constexpr float L2E2 = 2.8853900817779268f;  // 2/ln2: exp(2c)=exp2(c*L2E2)
constexpr int WPB = 4;                       // waves per block
constexpr int NSH = 8;                       // shadow buffers
constexpr int SLAB_ROWS = ROWS / 8;          // 4096 rows = 4 MB bf16
constexpr int GSIG_OFF = 0;
constexpr int TSUM_OFF = ITERS * COLS;
// mid grid: 1024 blocks x 4 waves x 8 rows
constexpr int MID_BLOCKS = 1024;
constexpr int MID_RPW = 8;
// pass0/final grid: 2048 blocks x 4 waves x 4 rows (8 blocks/CU)
constexpr int BIG_BLOCKS = 2048;
constexpr int BIG_RPW = 4;

typedef float f4v __attribute__((ext_vector_type(4)));
}

__device__ __forceinline__ float bflo(unsigned u) {
  union { unsigned i; float f; } v; v.i = u << 16; return v.f;
}
__device__ __forceinline__ float bfhi(unsigned u) {
  union { unsigned i; float f; } v; v.i = u & 0xFFFF0000u; return v.f;
}
__device__ __forceinline__ unsigned f2bf(float f) {
  union { float f; unsigned u; } v; v.f = f;
  return (v.u + 0x7FFFu + ((v.u >> 16) & 1u)) >> 16;
}
// slab = bid&7 keeps each 4096-row panel on a stable XCD set across passes
__device__ __forceinline__ int row_base_mid(int bid, int wave) {
  return (bid & 7) * SLAB_ROWS + ((bid >> 3) * WPB + wave) * MID_RPW;
}
__device__ __forceinline__ int row_base_big(int bid, int wave) {
  return (bid & 7) * SLAB_ROWS + ((bid >> 3) * WPB + wave) * BIG_RPW;
}

// ---- zero: gsig[0] = 1/K; zero all tsum buffers ----
__global__ __launch_bounds__(256) void ipot_zero_kernel(float* __restrict__ ws) {
  const size_t stride = (size_t)gridDim.x * blockDim.x;
  const size_t gtid = (size_t)blockIdx.x * blockDim.x + threadIdx.x;
  if (gtid < COLS) ws[GSIG_OFF + gtid] = B_M;
  const size_t tsz = (size_t)(ITERS - 1) * NSH * COLS;
  for (size_t i = gtid; i < tsz; i += stride) ws[TSUM_OFF + i] = 0.0f;
}

// ---- pass0: Kb = bf16(exp(2C)) AND iteration 0 (sigma0 uniform) ----
__global__ __launch_bounds__(256, 8) void ipot_pass0_kernel(
    const float* __restrict__ C, float* __restrict__ out,
    float* __restrict__ ws) {
  __shared__ float part[WPB][COLS];
  const int tid = threadIdx.x;
  const int wave = tid >> 6;
  const int lane = tid & 63;
  const int wrow = row_base_big(blockIdx.x, wave);
  unsigned short* Kb = (unsigned short*)(out + (size_t)ROWS * COLS / 2);

  // PLAIN loads for C (leave caches warm where possible)
  f4v c0[BIG_RPW], c1[BIG_RPW];
#pragma unroll
  for (int r = 0; r < BIG_RPW; ++r) {
    const f4v* rp = (const f4v*)(C + (size_t)(wrow + r) * COLS);
    c0[r] = rp[2 * lane];
    c1[r] = rp[2 * lane + 1];
  }

  float p[BIG_RPW];
#pragma unroll
  for (int r = 0; r < BIG_RPW; ++r) {
    c0[r].x = exp2f(c0[r].x * L2E2); c0[r].y = exp2f(c0[r].y * L2E2);
    c0[r].z = exp2f(c0[r].z * L2E2); c0[r].w = exp2f(c0[r].w * L2E2);
    c1[r].x = exp2f(c1[r].x * L2E2); c1[r].y = exp2f(c1[r].y * L2E2);
    c1[r].z = exp2f(c1[r].z * L2E2); c1[r].w = exp2f(c1[r].w * L2E2);
    uint4 kp;
    kp.x = f2bf(c0[r].x) | (f2bf(c0[r].y) << 16);
    kp.y = f2bf(c0[r].z) | (f2bf(c0[r].w) << 16);
    kp.z = f2bf(c1[r].x) | (f2bf(c1[r].y) << 16);
    kp.w = f2bf(c1[r].z) | (f2bf(c1[r].w) << 16);
    ((uint4*)(Kb + (size_t)(wrow + r) * COLS))[lane] = kp;
    p[r] = ((c0[r].x + c0[r].y) + (c0[r].z + c0[r].w)) +
           ((c1[r].x + c1[r].y) + (c1[r].z + c1[r].w));
  }
#pragma unroll
  for (int off = 32; off; off >>= 1) {
#pragma unroll
    for (int r = 0; r < BIG_RPW; ++r) p[r] += __shfl_xor(p[r], off, 64);
  }
  float a[8] = {0.f, 0.f, 0.f, 0.f, 0.f, 0.f, 0.f, 0.f};
#pragma unroll
  for (int r = 0; r < BIG_RPW; ++r) {
    const float inv = 1.0f / (B_M * p[r] + EPS);  // r_i = B*sum(e)
    a[0] += c0[r].x * inv; a[1] += c0[r].y * inv;
    a[2] += c0[r].z * inv; a[3] += c0[r].w * inv;
    a[4] += c1[r].x * inv; a[5] += c1[r].y * inv;
    a[6] += c1[r].z * inv; a[7] += c1[r].w * inv;
  }
  *(float4*)&part[wave][8 * lane] = *(float4*)&a[0];
  *(float4*)&part[wave][8 * lane + 4] = *(float4*)&a[4];
  __syncthreads();
  float* ts = ws + TSUM_OFF + (size_t)(blockIdx.x & 7) * COLS;
  int j = tid;
  atomicAdd(&ts[j], part[0][j] + part[1][j] + part[2][j] + part[3][j]);
  j += 256;
  atomicAdd(&ts[j], part[0][j] + part[1][j] + part[2][j] + part[3][j]);
}

// ---- mid pass t (t=1..18): preamble sigma_t, stream bf16 Kb, tsum[t] ----
__global__ __launch_bounds__(256, 4) void ipot_mid_kernel(
    const float* __restrict__ base, float* __restrict__ ws, int t) {
  __shared__ float sig[COLS];
  __shared__ float part[WPB][COLS];
  const int tid = threadIdx.x;
  const int wave = tid >> 6;
  const int lane = tid & 63;
  const int wrow = row_base_mid(blockIdx.x, wave);
  const unsigned short* Kb =
      (const unsigned short*)(base + (size_t)ROWS * COLS / 2);

  // critical-path loads FIRST (vmcnt is ordered: sigma compute then waits
  // only on these 18 loads, with the 8 Kb loads still in flight behind)
  const float* gsp = ws + GSIG_OFF + (size_t)(t - 1) * COLS;
  const float* tb = ws + TSUM_OFF + (size_t)(t - 1) * NSH * COLS;
  float tv0[NSH], tv1[NSH];
#pragma unroll
  for (int s = 0; s < NSH; ++s) {
    tv0[s] = tb[s * COLS + tid];
    tv1[s] = tb[s * COLS + tid + 256];
  }
  const float g0 = gsp[tid];
  const float g1 = gsp[tid + 256];

  uint4 kr[MID_RPW];
#pragma unroll
  for (int r = 0; r < MID_RPW; ++r)
    kr[r] = ((const uint4*)(Kb + (size_t)(wrow + r) * COLS))[lane];

  {
    float T0 = 0.f, T1 = 0.f;
#pragma unroll
    for (int s = 0; s < NSH; ++s) { T0 += tv0[s]; T1 += tv1[s]; }
    const float sv0 = B_M / (g0 * A_M * T0 + EPS);
    const float sv1 = B_M / (g1 * A_M * T1 + EPS);
    sig[tid] = sv0;
    sig[tid + 256] = sv1;
    if (blockIdx.x == 0) {
      float* gsc = ws + GSIG_OFF + (size_t)t * COLS;
      gsc[tid] = sv0;
      gsc[tid + 256] = sv1;
    }
  }
  __syncthreads();

  const float4 sA = *(const float4*)&sig[8 * lane];
  const float4 sB = *(const float4*)&sig[8 * lane + 4];

  float p[MID_RPW];
#pragma unroll
  for (int r = 0; r < MID_RPW; ++r) {
    p[r] = bflo(kr[r].x) * sA.x + bfhi(kr[r].x) * sA.y +
           bflo(kr[r].y) * sA.z + bfhi(kr[r].y) * sA.w +
           bflo(kr[r].z) * sB.x + bfhi(kr[r].z) * sB.y +
           bflo(kr[r].w) * sB.z + bfhi(kr[r].w) * sB.w;
  }
#pragma unroll
  for (int off = 32; off; off >>= 1) {
#pragma unroll
    for (int r = 0; r < MID_RPW; ++r) p[r] += __shfl_xor(p[r], off, 64);
  }
  float a[8] = {0.f, 0.f, 0.f, 0.f, 0.f, 0.f, 0.f, 0.f};
#pragma unroll
  for (int r = 0; r < MID_RPW; ++r) {
    const float inv = 1.0f / (p[r] + EPS);
    a[0] += bflo(kr[r].x) * inv; a[1] += bfhi(kr[r].x) * inv;
    a[2] += bflo(kr[r].y) * inv; a[3] += bfhi(kr[r].y) * inv;
    a[4] += bflo(kr[r].z) * inv; a[5] += bfhi(kr[r].z) * inv;
    a[6] += bflo(kr[r].w) * inv; a[7] += bfhi(kr[r].w) * inv;
  }
  *(float4*)&part[wave][8 * lane] = *(float4*)&a[0];
  *(float4*)&part[wave][8 * lane + 4] = *(float4*)&a[4];
  __syncthreads();
  float* ts = ws + TSUM_OFF +
              ((size_t)t * NSH + (blockIdx.x & 7)) * COLS;
  int j = tid;
  atomicAdd(&ts[j], part[0][j] + part[1][j] + part[2][j] + part[3][j]);
  j += 256;
  atomicAdd(&ts[j], part[0][j] + part[1][j] + part[2][j] + part[3][j]);
}

// ---- final (iteration 19): preamble sigma_19, fp32 exp, write Q*n ----
__global__ __launch_bounds__(256, 8) void ipot_final_kernel(
    const float* __restrict__ C, float* __restrict__ out,
    const float* __restrict__ ws) {
  __shared__ float sig[COLS];
  const int tid = threadIdx.x;
  const int wave = tid >> 6;
  const int lane = tid & 63;
  const int wrow = row_base_big(blockIdx.x, wave);

  // preamble loads first (critical path), then C loads
  const int t = ITERS - 1;  // 19
  const float* gsp = ws + GSIG_OFF + (size_t)(t - 1) * COLS;
  const float* tb = ws + TSUM_OFF + (size_t)(t - 1) * NSH * COLS;
  float tv0[NSH], tv1[NSH];
#pragma unroll
  for (int s = 0; s < NSH; ++s) {
    tv0[s] = tb[s * COLS + tid];
    tv1[s] = tb[s * COLS + tid + 256];
  }
  const float g0 = gsp[tid];
  const float g1 = gsp[tid + 256];

  f4v c0[BIG_RPW], c1[BIG_RPW];
#pragma unroll
  for (int r = 0; r < BIG_RPW; ++r) {
    const f4v* rp = (const f4v*)(C + (size_t)(wrow + r) * COLS);
    c0[r] = rp[2 * lane];
    c1[r] = rp[2 * lane + 1];
  }

  {
    float T0 = 0.f, T1 = 0.f;
#pragma unroll
    for (int s = 0; s < NSH; ++s) { T0 += tv0[s]; T1 += tv1[s]; }
    sig[tid] = B_M / (g0 * A_M * T0 + EPS);
    sig[tid + 256] = B_M / (g1 * A_M * T1 + EPS);
  }
  __syncthreads();

  const float4 sA = *(const float4*)&sig[8 * lane];
  const float4 sB = *(const float4*)&sig[8 * lane + 4];

  float p[BIG_RPW];
#pragma unroll
  for (int r = 0; r < BIG_RPW; ++r) {
    c0[r].x = exp2f(c0[r].x * L2E2); c0[r].y = exp2f(c0[r].y * L2E2);
    c0[r].z = exp2f(c0[r].z * L2E2); c0[r].w = exp2f(c0[r].w * L2E2);
    c1[r].x = exp2f(c1[r].x * L2E2); c1[r].y = exp2f(c1[r].y * L2E2);
    c1[r].z = exp2f(c1[r].z * L2E2); c1[r].w = exp2f(c1[r].w * L2E2);
    p[r] = c0[r].x * sA.x + c0[r].y * sA.y + c0[r].z * sA.z + c0[r].w * sA.w +
           c1[r].x * sB.x + c1[r].y * sB.y + c1[r].z * sB.z + c1[r].w * sB.w;
  }
#pragma unroll
  for (int off = 32; off; off >>= 1) {
#pragma unroll
    for (int r = 0; r < BIG_RPW; ++r) p[r] += __shfl_xor(p[r], off, 64);
  }
#pragma unroll
  for (int r = 0; r < BIG_RPW; ++r) {
    const float inv = 1.0f / (p[r] + EPS);
    f4v* wp = (f4v*)(out + (size_t)(wrow + r) * COLS);
    f4v o0, o1;
    o0.x = c0[r].x * sA.x * inv; o0.y = c0[r].y * sA.y * inv;
    o0.z = c0[r].z * sA.z * inv; o0.w = c0[r].w * sA.w * inv;
    o1.x = c1[r].x * sB.x * inv; o1.y = c1[r].y * sB.y * inv;
    o1.z = c1[r].z * sB.z * inv; o1.w = c1[r].w * sB.w * inv;
    __builtin_nontemporal_store(o0, &wp[2 * lane]);
    __builtin_nontemporal_store(o1, &wp[2 * lane + 1]);
  }
}

extern "C" void kernel_launch(void* const* d_in, const int* in_sizes, int n_in,
                              void* d_out, int out_size, void* d_ws, size_t ws_size,
                              hipStream_t stream) {
  const float* C = (const float*)d_in[0];
  float* out = (float*)d_out;
  float* ws = (float*)d_ws;

  ipot_zero_kernel<<<128, 256, 0, stream>>>(ws);
  ipot_pass0_kernel<<<BIG_BLOCKS, 256, 0, stream>>>(C, out, ws);
  for (int t = 1; t < ITERS - 1; ++t)
    ipot_mid_kernel<<<MID_BLOCKS, 256, 0, stream>>>(out, ws, t);
  ipot_final_kernel<<<BIG_BLOCKS, 256, 0, stream>>>(C, out, ws);
}